// Round 10
// baseline (323.341 us; speedup 1.0000x reference)
//
#include <hip/hip_runtime.h>

#define B 8
#define NH 512
#define D 128
#define HEADS 4
#define ALPHA 0.2f

typedef short short8 __attribute__((ext_vector_type(8)));
typedef float f32x4 __attribute__((ext_vector_type(4)));
typedef unsigned short u16t;

__device__ __forceinline__ unsigned short f2b(float f) {
    union { float f; unsigned u; } v; v.f = f;
    unsigned r = v.u + 0x7FFFu + ((v.u >> 16) & 1u);
    return (unsigned short)(r >> 16);
}
__device__ __forceinline__ float lrelu(float x) { return fmaxf(x, ALPHA * x); }
// pack two f32 -> two bf16 (truncation) in one v_perm
__device__ __forceinline__ unsigned packbf(float a, float b) {
    union { float f; unsigned u; } ua, ub; ua.f = a; ub.f = b;
    return __builtin_amdgcn_perm(ub.u, ua.u, 0x07060302u);
}
// pack two f32 -> two bf16 with RNE rounding (matches f2b)
__device__ __forceinline__ unsigned packbf_rne(float a, float b) {
    return (unsigned)f2b(a) | ((unsigned)f2b(b) << 16);
}
__device__ __forceinline__ unsigned long long pack4_rne(f32x4 v) {
    return (unsigned long long)packbf_rne(v[0], v[1])
         | ((unsigned long long)packbf_rne(v[2], v[3]) << 32);
}

// ---- flag helpers: producer fence+inc, consumer acquire-spin --------------
__device__ __forceinline__ void flag_release(unsigned* f) {
    __threadfence();
    __syncthreads();
    if (threadIdx.x == 0)
        __hip_atomic_fetch_add(f, 1u, __ATOMIC_RELEASE, __HIP_MEMORY_SCOPE_AGENT);
}
__device__ __forceinline__ void flag_acquire(unsigned* f, unsigned target) {
    if (threadIdx.x == 0) {
        while (__hip_atomic_load(f, __ATOMIC_ACQUIRE, __HIP_MEMORY_SCOPE_AGENT) < target)
            __builtin_amdgcn_s_sleep(2);
    }
    __syncthreads();
    __threadfence();
}

// ============ P0: proj1 tile (r6 body) =====================================
__device__ __forceinline__ void proj1_body(int bid, int t,
    const float* __restrict__ hs, const float* __restrict__ os,
    const float* __restrict__ Wh, const float* __restrict__ Wo,
    const float* __restrict__ ah,
    u16t* __restrict__ h1T, u16t* __restrict__ WoT,
    float* __restrict__ f1, float* __restrict__ f2,
    u16t (&wlds)[128][136])
{
    int rt = bid >> 2, h = bid & 3;
    int rowG = rt * 64;
    int b = rowG >> 10;
    int w = t >> 6, l = t & 63, l15 = l & 15, g = l >> 4;

    // stage W[h]^T into LDS
    {
        const float* Whh = Wh + (size_t)h * 16384;
        #pragma unroll
        for (int i = 0; i < 32; ++i) {
            int p = i * 256 + t;
            int c = p & 127, k0 = (p >> 7) * 2;
            float w0 = Whh[(size_t)k0 * 128 + c];
            float w1 = Whh[(size_t)(k0 + 1) * 128 + c];
            *(unsigned*)&wlds[c][k0] = packbf_rne(w0, w1);
        }
    }
    // side job: emit WoT (128 blocks x 256 thr x 2 elems)
    if (bid < 128) {
        int idx = bid * 512 + t * 2;
        int c = idx >> 9, k = idx & 511;
        float w0 = Wo[(size_t)k * 128 + c];
        float w1 = Wo[(size_t)(k + 1) * 128 + c];
        *(unsigned*)&WoT[(size_t)c * 512 + k] = packbf_rne(w0, w1);
    }
    __syncthreads();

    int nA = rowG + w * 16 + l15;
    int nloc = nA & 1023;
    const float* xr = (nloc < NH) ? hs + ((size_t)(b * NH + nloc)) * 128
                                  : os + ((size_t)(b * NH + (nloc - NH))) * 128;

    f32x4 acc[8] = {};
    #pragma unroll
    for (int kc = 0; kc < 4; ++kc) {
        int k0 = kc * 32 + g * 8;
        float4 u0 = *(const float4*)&xr[k0];
        float4 u1 = *(const float4*)&xr[k0 + 4];
        union { unsigned u[4]; short8 s; } afu;
        afu.u[0] = packbf_rne(u0.x, u0.y);
        afu.u[1] = packbf_rne(u0.z, u0.w);
        afu.u[2] = packbf_rne(u1.x, u1.y);
        afu.u[3] = packbf_rne(u1.z, u1.w);
        short8 af = afu.s;
        #pragma unroll
        for (int ct = 0; ct < 8; ++ct) {
            short8 bfr = *(const short8*)&wlds[ct * 16 + l15][k0];
            acc[ct] = __builtin_amdgcn_mfma_f32_16x16x32_bf16(af, bfr, acc[ct], 0, 0, 0);
        }
    }

    int bh = b * HEADS + h;
    size_t hTbase = (size_t)bh * 131072;
    int nloc0 = (rowG & 1023) + w * 16 + g * 4;
    float pr1[4] = {0.f, 0.f, 0.f, 0.f}, pr2[4] = {0.f, 0.f, 0.f, 0.f};

    #pragma unroll
    for (int ct = 0; ct < 8; ++ct) {
        int c = ct * 16 + l15;
        *(unsigned long long*)&h1T[hTbase + (size_t)c * 1024 + nloc0] = pack4_rne(acc[ct]);
        float a1 = ah[h * 256 + c], a2 = ah[h * 256 + 128 + c];
        #pragma unroll
        for (int r = 0; r < 4; ++r) {
            pr1[r] = fmaf(acc[ct][r], a1, pr1[r]);
            pr2[r] = fmaf(acc[ct][r], a2, pr2[r]);
        }
    }
    #pragma unroll
    for (int r = 0; r < 4; ++r) {
        float v1 = pr1[r], v2 = pr2[r];
        #pragma unroll
        for (int m = 1; m <= 8; m <<= 1) {
            v1 += __shfl_xor(v1, m, 64);
            v2 += __shfl_xor(v2, m, 64);
        }
        if (l15 == 0) {
            f1[(size_t)bh * 1024 + nloc0 + r] = v1;
            f2[(size_t)bh * 1024 + nloc0 + r] = v2;
        }
    }
}

// ============ P2: proj2 tile (r6 body) =====================================
__device__ __forceinline__ void proj2_body(int bid, int t,
    const u16t* __restrict__ x2, const u16t* __restrict__ WoT,
    const float* __restrict__ ao,
    u16t* __restrict__ h2T, float* __restrict__ f1, float* __restrict__ f2)
{
    int rowG = bid * 64;
    int b = rowG >> 10;
    int w = t >> 6, l = t & 63, l15 = l & 15, g = l >> 4;

    int rowA = rowG + w * 16 + l15;

    f32x4 acc[8] = {};
    #pragma unroll
    for (int kc = 0; kc < 16; ++kc) {
        int k0 = kc * 32 + g * 8;
        short8 af = *(const short8*)&x2[(size_t)rowA * 512 + k0];
        #pragma unroll
        for (int ct = 0; ct < 8; ++ct) {
            short8 bfr = *(const short8*)&WoT[(ct * 16 + l15) * 512 + k0];
            acc[ct] = __builtin_amdgcn_mfma_f32_16x16x32_bf16(af, bfr, acc[ct], 0, 0, 0);
        }
    }

    size_t hTbase = (size_t)b * 131072;
    int nloc0 = (rowG & 1023) + w * 16 + g * 4;
    int rowOut0 = rowG + w * 16 + g * 4;
    float pr1[4] = {0.f, 0.f, 0.f, 0.f}, pr2[4] = {0.f, 0.f, 0.f, 0.f};

    #pragma unroll
    for (int ct = 0; ct < 8; ++ct) {
        int c = ct * 16 + l15;
        *(unsigned long long*)&h2T[hTbase + (size_t)c * 1024 + nloc0] = pack4_rne(acc[ct]);
        float a1 = ao[c], a2 = ao[128 + c];
        #pragma unroll
        for (int r = 0; r < 4; ++r) {
            pr1[r] = fmaf(acc[ct][r], a1, pr1[r]);
            pr2[r] = fmaf(acc[ct][r], a2, pr2[r]);
        }
    }
    #pragma unroll
    for (int r = 0; r < 4; ++r) {
        float v1 = pr1[r], v2 = pr2[r];
        #pragma unroll
        for (int m = 1; m <= 8; m <<= 1) {
            v1 += __shfl_xor(v1, m, 64);
            v2 += __shfl_xor(v2, m, 64);
        }
        if (l15 == 0) { f1[rowOut0 + r] = v1; f2[rowOut0 + r] = v2; }
    }
}

// ============ P1/P3: attn tile (r6 body) ===================================
__device__ __forceinline__ void attn_body(int mode, int wid, int t,
    const u16t* __restrict__ HT,
    const float* __restrict__ f1, const float* __restrict__ f2,
    u16t* __restrict__ x2, float* __restrict__ dout,
    u16t (&hbuf)[2][128][40], float (&f2s)[512], float (&red4)[4])
{
    int w4 = t >> 6, l = t & 63, l15 = l & 15, g = l >> 4;
    int itile, side, z, b, h;
    if (mode == 0) {
        int xcd = wid & 7, jj = (wid >> 3) & 7;
        itile = wid >> 6;
        int q = xcd * 8 + jj;
        z = q >> 1; side = q & 1; b = z >> 2; h = z & 3;
    } else {
        b = wid & 7; itile = wid >> 3; side = 0; z = b; h = 0;
    }
    bool self = (side == 0);
    int nbBase = self ? 512 : 0;
    size_t HTbase = (size_t)z * 131072;
    size_t fbase = (size_t)z * 1024;

    f2s[t] = f2[fbase + nbBase + t];
    f2s[t + 256] = f2[fbase + nbBase + t + 256];
    __syncthreads();
    float mv = fmaxf(f2s[t], f2s[t + 256]);
    #pragma unroll
    for (int m = 1; m <= 32; m <<= 1) mv = fmaxf(mv, __shfl_xor(mv, m, 64));
    if (l == 0) red4[w4] = mv;
    __syncthreads();
    float M = fmaxf(fmaxf(red4[0], red4[1]), fmaxf(red4[2], red4[3]));

    int i0 = itile * 64 + w4 * 16;
    int i = i0 + l15;
    int n = side * 512 + i;
    float fv = f1[fbase + n];
    float mr = lrelu(fv + M);
    float z0 = 0.f;
    if (self) {
        float sc = lrelu(fv + f2[fbase + i]);
        mr = fmaxf(mr, sc);
        z0 = __expf(sc - mr);
    }
    float zacc = (g == 0) ? z0 : 0.f;

    {
        int c = t >> 1, ks = (t & 1) * 16;
        const u16t* src = &HT[HTbase + (size_t)c * 1024 + nbBase + ks];
        *(short8*)&hbuf[0][c][ks] = *(const short8*)src;
        *(short8*)&hbuf[0][c][ks + 8] = *(const short8*)(src + 8);
    }
    __syncthreads();

    f32x4 acc[8] = {};
    int cS = t >> 1, ksS = (t & 1) * 16;

    for (int jt = 0; jt < 16; ++jt) {
        int cur = jt & 1;
        short8 s0, s1;
        if (jt < 15) {
            const u16t* src = &HT[HTbase + (size_t)cS * 1024 + nbBase + (jt + 1) * 32 + ksS];
            s0 = *(const short8*)src;
            s1 = *(const short8*)(src + 8);
        }
        int j0 = jt * 32 + g * 8;
        float p[8];
        #pragma unroll
        for (int qq = 0; qq < 8; ++qq) {
            float tq = fv + f2s[j0 + qq];
            float ev = fmaxf(tq, ALPHA * tq);
            p[qq] = __expf(ev - mr);
            zacc += p[qq];
        }
        union { unsigned u[4]; short8 s; } pfu;
        pfu.u[0] = packbf(p[0], p[1]);
        pfu.u[1] = packbf(p[2], p[3]);
        pfu.u[2] = packbf(p[4], p[5]);
        pfu.u[3] = packbf(p[6], p[7]);
        short8 pf = pfu.s;
        #pragma unroll
        for (int ct = 0; ct < 8; ++ct) {
            short8 hf = *(const short8*)&hbuf[cur][ct * 16 + l15][g * 8];
            acc[ct] = __builtin_amdgcn_mfma_f32_16x16x32_bf16(hf, pf, acc[ct], 0, 0, 0);
        }
        if (jt < 15) {
            *(short8*)&hbuf[cur ^ 1][cS][ksS] = s0;
            *(short8*)&hbuf[cur ^ 1][cS][ksS + 8] = s1;
        }
        __syncthreads();
    }

    // self-loop via diagonal-B MFMA
    if (self) {
        unsigned short z0b = f2b(z0);
        short8 pfs;
        #pragma unroll
        for (int qq = 0; qq < 8; ++qq)
            pfs[qq] = (short)((g * 8 + qq == l15) ? z0b : 0);
        int sc0 = side * 512 + i0;
        #pragma unroll
        for (int ct = 0; ct < 8; ++ct) {
            short8 hfs = *(const short8*)&HT[HTbase + (size_t)(ct * 16 + l15) * 1024 + sc0 + g * 8];
            acc[ct] = __builtin_amdgcn_mfma_f32_16x16x32_bf16(hfs, pfs, acc[ct], 0, 0, 0);
        }
    }

    zacc += __shfl_xor(zacc, 16, 64);
    zacc += __shfl_xor(zacc, 32, 64);
    float zinv = 1.f / zacc;

    if (mode == 0) {
        size_t orow = ((size_t)(b * 1024 + n)) * 512 + h * 128;
        #pragma unroll
        for (int ct = 0; ct < 8; ++ct) {
            int c0 = ct * 16 + g * 4;
            float o[4];
            #pragma unroll
            for (int r = 0; r < 4; ++r) {
                float v = acc[ct][r] * zinv;
                o[r] = v > 0.f ? v : __expf(v) - 1.f;
            }
            unsigned long long pv =
                  (unsigned long long)packbf_rne(o[0], o[1])
                | ((unsigned long long)packbf_rne(o[2], o[3]) << 32);
            *(unsigned long long*)&x2[orow + c0] = pv;
        }
    } else {
        float o[8][4];
        float mx = -3.0e38f;
        #pragma unroll
        for (int ct = 0; ct < 8; ++ct) {
            #pragma unroll
            for (int r = 0; r < 4; ++r) {
                float v = acc[ct][r] * zinv;
                v = v > 0.f ? v : __expf(v) - 1.f;
                o[ct][r] = v;
                mx = fmaxf(mx, v);
            }
        }
        mx = fmaxf(mx, __shfl_xor(mx, 16, 64));
        mx = fmaxf(mx, __shfl_xor(mx, 32, 64));
        float s = 0.f;
        #pragma unroll
        for (int ct = 0; ct < 8; ++ct)
            #pragma unroll
            for (int r = 0; r < 4; ++r) s += __expf(o[ct][r] - mx);
        s += __shfl_xor(s, 16, 64);
        s += __shfl_xor(s, 32, 64);
        float lse = mx + __logf(s);
        #pragma unroll
        for (int ct = 0; ct < 8; ++ct) {
            float4 st = {o[ct][0] - lse, o[ct][1] - lse, o[ct][2] - lse, o[ct][3] - lse};
            *(float4*)&dout[((size_t)(b * 512 + i)) * 128 + ct * 16 + g * 4] = st;
        }
    }
}

// ============ mega: all 4 phases, flag-barrier ordered =====================
// 512 blocks x 256 thr = 2 blocks/CU guaranteed co-resident
// (LDS 57.4KB/block -> 114.7KB/CU < 160KB), so spin-waits cannot deadlock.
__global__ __launch_bounds__(256) void mega_kernel(
    const float* __restrict__ hs, const float* __restrict__ os,
    const float* __restrict__ Wh, const float* __restrict__ ah,
    const float* __restrict__ Wo, const float* __restrict__ ao,
    float* __restrict__ dout,
    u16t* __restrict__ h1T, u16t* __restrict__ x2, u16t* __restrict__ h2T,
    u16t* __restrict__ WoT,
    float* __restrict__ f1a, float* __restrict__ f2a,
    float* __restrict__ f1b, float* __restrict__ f2b_,
    unsigned* __restrict__ flags)
{
    __shared__ __align__(16) u16t wlds[128][136];
    __shared__ __align__(16) u16t hbuf[2][128][40];
    __shared__ __align__(16) float f2s[512];
    __shared__ float red4[4];

    int bid = blockIdx.x, t = threadIdx.x;

    // P0: proj1 (512 tiles)
    proj1_body(bid, t, hs, os, Wh, Wo, ah, h1T, WoT, f1a, f2a, wlds);
    flag_release(&flags[0]);

    // P1: attn0 (512 tiles)
    flag_acquire(&flags[0], 512);
    attn_body(0, bid, t, h1T, f1a, f2a, x2, nullptr, hbuf, f2s, red4);
    flag_release(&flags[1]);

    // P2: proj2 (128 tiles)
    if (bid < 128) {
        flag_acquire(&flags[1], 512);
        proj2_body(bid, t, x2, WoT, ao, h2T, f1b, f2b_);
        flag_release(&flags[2]);
    }

    // P3: attn1 (64 tiles)
    if (bid < 64) {
        flag_acquire(&flags[2], 128);
        attn_body(1, bid, t, h2T, f1b, f2b_, nullptr, dout, hbuf, f2s, red4);
    }
}

extern "C" void kernel_launch(void* const* d_in, const int* in_sizes, int n_in,
                              void* d_out, int out_size, void* d_ws, size_t ws_size,
                              hipStream_t stream)
{
    const float* hs = (const float*)d_in[0];
    const float* os = (const float*)d_in[1];
    const float* Wh = (const float*)d_in[4];
    const float* ah = (const float*)d_in[5];
    const float* Wo = (const float*)d_in[6];
    const float* ao = (const float*)d_in[7];
    float* out = (float*)d_out;

    u16t* h1T = (u16t*)d_ws;             // 4,194,304 u16
    u16t* x2  = h1T + 4194304;           // 4,194,304 u16
    u16t* h2T = x2 + 4194304;            // 1,048,576 u16
    u16t* WoT = h2T + 1048576;           // 65,536 u16
    float* f1a = (float*)(WoT + 65536);  // 32,768 f32
    float* f2a = f1a + 32768;
    float* f1b = f2a + 32768;            // 8,192 f32
    float* f2b_ = f1b + 8192;
    unsigned* flags = (unsigned*)(f2b_ + 8192);   // 4 u32

    hipMemsetAsync(flags, 0, 16, stream);
    mega_kernel<<<512, 256, 0, stream>>>(hs, os, Wh, ah, Wo, ao, out,
                                         h1T, x2, h2T, WoT,
                                         f1a, f2a, f1b, f2b_, flags);
}

// Round 12
// 64.684 us; speedup vs baseline: 4.9988x; 4.9988x over previous
//
#include <hip/hip_runtime.h>

#define B 8
#define NH 512
#define D 128
#define HEADS 4
#define ALPHA 0.2f

typedef short short8 __attribute__((ext_vector_type(8)));
typedef float f32x4 __attribute__((ext_vector_type(4)));
typedef unsigned short u16t;

__device__ __forceinline__ unsigned short f2b(float f) {
    union { float f; unsigned u; } v; v.f = f;
    unsigned r = v.u + 0x7FFFu + ((v.u >> 16) & 1u);
    return (unsigned short)(r >> 16);
}
__device__ __forceinline__ float lrelu(float x) { return fmaxf(x, ALPHA * x); }
// pack two f32 -> two bf16 (truncation) in one v_perm
__device__ __forceinline__ unsigned packbf(float a, float b) {
    union { float f; unsigned u; } ua, ub; ua.f = a; ub.f = b;
    return __builtin_amdgcn_perm(ub.u, ua.u, 0x07060302u);
}
// pack two f32 -> two bf16 with RNE rounding (matches f2b)
__device__ __forceinline__ unsigned packbf_rne(float a, float b) {
    return (unsigned)f2b(a) | ((unsigned)f2b(b) << 16);
}
__device__ __forceinline__ unsigned long long pack4_rne(f32x4 v) {
    return (unsigned long long)packbf_rne(v[0], v[1])
         | ((unsigned long long)packbf_rne(v[2], v[3]) << 32);
}

// ============ proj1: h1T[bh][c][n] = (x @ Wh)^T, + f1a/f2a =================
// grid 256 (64 row-tiles of 128 x 4 heads), 512 thr.
// Side-jobs: bid<64 emit WoT; all blocks zero h2acc; bid<8 zero f1b/f2b.
__global__ __launch_bounds__(512) void proj1_kernel(
    const float* __restrict__ hs, const float* __restrict__ os,
    const float* __restrict__ Wh, const float* __restrict__ Wo,
    const float* __restrict__ ah,
    u16t* __restrict__ h1T, u16t* __restrict__ WoT,
    float* __restrict__ f1, float* __restrict__ f2,
    float* __restrict__ h2acc, float* __restrict__ f1b2b)
{
    int bid = blockIdx.x;
    int rt = bid >> 2, h = bid & 3;
    int rowG = rt * 128;
    int b = rowG >> 10;
    int t = threadIdx.x;
    int w = t >> 6, l = t & 63, l15 = l & 15, g = l >> 4;

    __shared__ __align__(16) u16t wlds[128][136];   // [c][k], pad 8

    // zero h2acc: 1,048,576 f32 / 256 blocks = 4096 f32 per block
    {
        float4 z4 = {0.f, 0.f, 0.f, 0.f};
        float4* dst = (float4*)(h2acc + (size_t)bid * 4096);
        dst[t] = z4;
        dst[t + 512] = z4;
    }
    // zero f1b/f2b (16384 f32 contiguous)
    if (bid < 8) {
        float4 z4 = {0.f, 0.f, 0.f, 0.f};
        ((float4*)f1b2b)[bid * 512 + t] = z4;
    }

    // stage W[h]^T into LDS: 8192 pairs / 512 thr = 16 iters
    {
        const float* Whh = Wh + (size_t)h * 16384;
        #pragma unroll
        for (int i = 0; i < 16; ++i) {
            int p = i * 512 + t;
            int c = p & 127, k0 = (p >> 7) * 2;
            float w0 = Whh[(size_t)k0 * 128 + c];
            float w1 = Whh[(size_t)(k0 + 1) * 128 + c];
            *(unsigned*)&wlds[c][k0] = packbf_rne(w0, w1);
        }
    }
    // side job: emit WoT (64 blocks x 512 thr x 2 elems = 65536)
    if (bid < 64) {
        int idx = bid * 1024 + t * 2;
        int c = idx >> 9, k = idx & 511;
        float w0 = Wo[(size_t)k * 128 + c];
        float w1 = Wo[(size_t)(k + 1) * 128 + c];
        *(unsigned*)&WoT[(size_t)c * 512 + k] = packbf_rne(w0, w1);
    }
    __syncthreads();

    int nA = rowG + w * 16 + l15;
    int nloc = nA & 1023;
    const float* xr = (nloc < NH) ? hs + ((size_t)(b * NH + nloc)) * 128
                                  : os + ((size_t)(b * NH + (nloc - NH))) * 128;

    f32x4 acc[8] = {};
    #pragma unroll
    for (int kc = 0; kc < 4; ++kc) {
        int k0 = kc * 32 + g * 8;
        float4 u0 = *(const float4*)&xr[k0];
        float4 u1 = *(const float4*)&xr[k0 + 4];
        union { unsigned u[4]; short8 s; } afu;
        afu.u[0] = packbf_rne(u0.x, u0.y);
        afu.u[1] = packbf_rne(u0.z, u0.w);
        afu.u[2] = packbf_rne(u1.x, u1.y);
        afu.u[3] = packbf_rne(u1.z, u1.w);
        short8 af = afu.s;
        #pragma unroll
        for (int ct = 0; ct < 8; ++ct) {
            short8 bfr = *(const short8*)&wlds[ct * 16 + l15][k0];
            acc[ct] = __builtin_amdgcn_mfma_f32_16x16x32_bf16(af, bfr, acc[ct], 0, 0, 0);
        }
    }

    int bh = b * HEADS + h;
    size_t hTbase = (size_t)bh * 131072;
    int nloc0 = (rowG & 1023) + w * 16 + g * 4;
    float pr1[4] = {0.f, 0.f, 0.f, 0.f}, pr2[4] = {0.f, 0.f, 0.f, 0.f};

    #pragma unroll
    for (int ct = 0; ct < 8; ++ct) {
        int c = ct * 16 + l15;
        *(unsigned long long*)&h1T[hTbase + (size_t)c * 1024 + nloc0] = pack4_rne(acc[ct]);
        float a1 = ah[h * 256 + c], a2 = ah[h * 256 + 128 + c];
        #pragma unroll
        for (int r = 0; r < 4; ++r) {
            pr1[r] = fmaf(acc[ct][r], a1, pr1[r]);
            pr2[r] = fmaf(acc[ct][r], a2, pr2[r]);
        }
    }
    #pragma unroll
    for (int r = 0; r < 4; ++r) {
        float v1 = pr1[r], v2 = pr2[r];
        #pragma unroll
        for (int m = 1; m <= 8; m <<= 1) {
            v1 += __shfl_xor(v1, m, 64);
            v2 += __shfl_xor(v2, m, 64);
        }
        if (l15 == 0) {
            f1[(size_t)bh * 1024 + nloc0 + r] = v1;
            f2[(size_t)bh * 1024 + nloc0 + r] = v2;
        }
    }
}

// ============ attn0: layer-1 attention + fused proj2 partials ==============
// 512 blocks (XCD-swizzled). Epilogue: per-head partial GEMM vs WoT slice,
// h2acc[b][c][n] += partial (f32 atomics); f1b/f2b += partial dots (atomics).
__global__ __launch_bounds__(256) void attn0_kernel(
    const u16t* __restrict__ HT,                    // [Z][128][1024] bf16
    const float* __restrict__ f1, const float* __restrict__ f2,  // [Z][1024]
    const u16t* __restrict__ WoT, const float* __restrict__ ao,
    float* __restrict__ h2acc,                      // [B][128][1024] f32
    float* __restrict__ f1bg, float* __restrict__ f2bg)  // [B*1024] each
{
    __shared__ __align__(16) u16t hbuf[2][128][40];
    __shared__ __align__(16) u16t x2t[4][16][136];  // per-wave x2 tile [n][k]
    __shared__ __align__(16) float f2s[512];
    __shared__ float red4[4];

    int t = threadIdx.x, w4 = t >> 6, l = t & 63, l15 = l & 15, g = l >> 4;
    int wid = blockIdx.x;
    int xcd = wid & 7, jj = (wid >> 3) & 7;
    int itile = wid >> 6;
    int q = xcd * 8 + jj;
    int z = q >> 1, side = q & 1;
    int b = z >> 2, h = z & 3;
    bool self = (side == 0);
    int nbBase = self ? 512 : 0;
    size_t HTbase = (size_t)z * 131072;
    size_t fbase = (size_t)z * 1024;

    f2s[t] = f2[fbase + nbBase + t];
    f2s[t + 256] = f2[fbase + nbBase + t + 256];
    __syncthreads();
    float mv = fmaxf(f2s[t], f2s[t + 256]);
    #pragma unroll
    for (int m = 1; m <= 32; m <<= 1) mv = fmaxf(mv, __shfl_xor(mv, m, 64));
    if (l == 0) red4[w4] = mv;
    __syncthreads();
    float M = fmaxf(fmaxf(red4[0], red4[1]), fmaxf(red4[2], red4[3]));

    int i0 = itile * 64 + w4 * 16;
    int i = i0 + l15;
    int n = side * 512 + i;
    float fv = f1[fbase + n];
    float mr = lrelu(fv + M);
    float z0 = 0.f;
    if (self) {
        float sc = lrelu(fv + f2[fbase + i]);
        mr = fmaxf(mr, sc);
        z0 = __expf(sc - mr);
    }
    float zacc = (g == 0) ? z0 : 0.f;

    {
        int c = t >> 1, ks = (t & 1) * 16;
        const u16t* src = &HT[HTbase + (size_t)c * 1024 + nbBase + ks];
        *(short8*)&hbuf[0][c][ks] = *(const short8*)src;
        *(short8*)&hbuf[0][c][ks + 8] = *(const short8*)(src + 8);
    }
    __syncthreads();

    f32x4 acc[8] = {};
    int cS = t >> 1, ksS = (t & 1) * 16;

    for (int jt = 0; jt < 16; ++jt) {
        int cur = jt & 1;
        short8 s0, s1;
        if (jt < 15) {
            const u16t* src = &HT[HTbase + (size_t)cS * 1024 + nbBase + (jt + 1) * 32 + ksS];
            s0 = *(const short8*)src;
            s1 = *(const short8*)(src + 8);
        }
        int j0 = jt * 32 + g * 8;
        float p[8];
        #pragma unroll
        for (int qq = 0; qq < 8; ++qq) {
            float tq = fv + f2s[j0 + qq];
            float ev = fmaxf(tq, ALPHA * tq);
            p[qq] = __expf(ev - mr);
            zacc += p[qq];
        }
        union { unsigned u[4]; short8 s; } pfu;
        pfu.u[0] = packbf(p[0], p[1]);
        pfu.u[1] = packbf(p[2], p[3]);
        pfu.u[2] = packbf(p[4], p[5]);
        pfu.u[3] = packbf(p[6], p[7]);
        short8 pf = pfu.s;
        #pragma unroll
        for (int ct = 0; ct < 8; ++ct) {
            short8 hf = *(const short8*)&hbuf[cur][ct * 16 + l15][g * 8];
            acc[ct] = __builtin_amdgcn_mfma_f32_16x16x32_bf16(hf, pf, acc[ct], 0, 0, 0);
        }
        if (jt < 15) {
            *(short8*)&hbuf[cur ^ 1][cS][ksS] = s0;
            *(short8*)&hbuf[cur ^ 1][cS][ksS + 8] = s1;
        }
        __syncthreads();
    }

    // self-loop via diagonal-B MFMA
    if (self) {
        unsigned short z0b = f2b(z0);
        short8 pfs;
        #pragma unroll
        for (int qq = 0; qq < 8; ++qq)
            pfs[qq] = (short)((g * 8 + qq == l15) ? z0b : 0);
        int sc0 = side * 512 + i0;
        #pragma unroll
        for (int ct = 0; ct < 8; ++ct) {
            short8 hfs = *(const short8*)&HT[HTbase + (size_t)(ct * 16 + l15) * 1024 + sc0 + g * 8];
            acc[ct] = __builtin_amdgcn_mfma_f32_16x16x32_bf16(hfs, pfs, acc[ct], 0, 0, 0);
        }
    }

    zacc += __shfl_xor(zacc, 16, 64);
    zacc += __shfl_xor(zacc, 32, 64);
    float zinv = 1.f / zacc;

    // x2 tile (elu'd, bf16) -> wave-local LDS [n][k] (no barrier needed:
    // each wave reads only its own x2t[w4])
    #pragma unroll
    for (int ct = 0; ct < 8; ++ct) {
        float o[4];
        #pragma unroll
        for (int r = 0; r < 4; ++r) {
            float v = acc[ct][r] * zinv;
            o[r] = v > 0.f ? v : __expf(v) - 1.f;
        }
        unsigned long long pv =
              (unsigned long long)packbf_rne(o[0], o[1])
            | ((unsigned long long)packbf_rne(o[2], o[3]) << 32);
        *(unsigned long long*)&x2t[w4][l15][ct * 16 + g * 4] = pv;
    }

    // wave-local partial GEMM: A = WoT head-slice rows c2, B = x2t cols n
    f32x4 acc2[8] = {};
    const u16t* wop = WoT + h * 128;
    #pragma unroll
    for (int kc = 0; kc < 4; ++kc) {
        short8 bfr = *(const short8*)&x2t[w4][l15][kc * 32 + g * 8];
        #pragma unroll
        for (int ct2 = 0; ct2 < 8; ++ct2) {
            short8 af = *(const short8*)&wop[(size_t)(ct2 * 16 + l15) * 512 + kc * 32 + g * 8];
            acc2[ct2] = __builtin_amdgcn_mfma_f32_16x16x32_bf16(af, bfr, acc2[ct2], 0, 0, 0);
        }
    }
    // h2 partial accumulate (lane l15 = n-col, coalesced)
    float* hp = h2acc + (size_t)b * 131072;
    #pragma unroll
    for (int ct2 = 0; ct2 < 8; ++ct2) {
        #pragma unroll
        for (int r = 0; r < 4; ++r) {
            int c2 = ct2 * 16 + g * 4 + r;
            atomicAdd(hp + (size_t)c2 * 1024 + n, acc2[ct2][r]);
        }
    }
    // f1b/f2b partial dots over this head's c-slice (ao is L1-resident)
    {
        float v1 = 0.f, v2 = 0.f;
        #pragma unroll
        for (int ct2 = 0; ct2 < 8; ++ct2) {
            float4 a1q = *(const float4*)&ao[ct2 * 16 + g * 4];
            float4 a2q = *(const float4*)&ao[128 + ct2 * 16 + g * 4];
            v1 += acc2[ct2][0] * a1q.x + acc2[ct2][1] * a1q.y
                + acc2[ct2][2] * a1q.z + acc2[ct2][3] * a1q.w;
            v2 += acc2[ct2][0] * a2q.x + acc2[ct2][1] * a2q.y
                + acc2[ct2][2] * a2q.z + acc2[ct2][3] * a2q.w;
        }
        v1 += __shfl_xor(v1, 16, 64); v1 += __shfl_xor(v1, 32, 64);
        v2 += __shfl_xor(v2, 16, 64); v2 += __shfl_xor(v2, 32, 64);
        if (g == 0) {
            atomicAdd(&f1bg[b * 1024 + n], v1);
            atomicAdd(&f2bg[b * 1024 + n], v2);
        }
    }
}

// ============ attn1: layer-2 attention over f32 h2acc ======================
// 64 blocks (8 b x 8 itiles of 64 humans). f1b/f2b precomputed (atomics).
__global__ __launch_bounds__(256) void attn1_kernel(
    const float* __restrict__ h2acc,                // [B][128][1024] f32
    const float* __restrict__ f1bg, const float* __restrict__ f2bg,
    float* __restrict__ dout)
{
    __shared__ __align__(16) u16t hbuf[2][128][40];
    __shared__ __align__(16) float f2s[512];
    __shared__ float red4[4];

    int t = threadIdx.x, w4 = t >> 6, l = t & 63, l15 = l & 15, g = l >> 4;
    int b = blockIdx.x & 7, itile = blockIdx.x >> 3;
    const float* h2 = h2acc + (size_t)b * 131072;

    f2s[t] = f2bg[b * 1024 + 512 + t];
    f2s[t + 256] = f2bg[b * 1024 + 768 + t];
    __syncthreads();
    float mv = fmaxf(f2s[t], f2s[t + 256]);
    #pragma unroll
    for (int m = 1; m <= 32; m <<= 1) mv = fmaxf(mv, __shfl_xor(mv, m, 64));
    if (l == 0) red4[w4] = mv;
    __syncthreads();
    float M = fmaxf(fmaxf(red4[0], red4[1]), fmaxf(red4[2], red4[3]));

    int i0 = itile * 64 + w4 * 16;
    int i = i0 + l15;
    float fv = f1bg[b * 1024 + i];
    float mr = lrelu(fv + M);
    float sc = lrelu(fv + f2bg[b * 1024 + i]);
    mr = fmaxf(mr, sc);
    float z0 = __expf(sc - mr);
    float zacc = (g == 0) ? z0 : 0.f;

    // prologue: stage chunk 0 (f32 -> bf16)
    int cS = t >> 1, ksS = (t & 1) * 16;
    {
        const float* src = h2 + (size_t)cS * 1024 + 512 + ksS;
        float4 q0 = *(const float4*)(src + 0);
        float4 q1 = *(const float4*)(src + 4);
        float4 q2 = *(const float4*)(src + 8);
        float4 q3 = *(const float4*)(src + 12);
        union { unsigned u[8]; short8 s[2]; } pk;
        pk.u[0] = packbf_rne(q0.x, q0.y); pk.u[1] = packbf_rne(q0.z, q0.w);
        pk.u[2] = packbf_rne(q1.x, q1.y); pk.u[3] = packbf_rne(q1.z, q1.w);
        pk.u[4] = packbf_rne(q2.x, q2.y); pk.u[5] = packbf_rne(q2.z, q2.w);
        pk.u[6] = packbf_rne(q3.x, q3.y); pk.u[7] = packbf_rne(q3.z, q3.w);
        *(short8*)&hbuf[0][cS][ksS] = pk.s[0];
        *(short8*)&hbuf[0][cS][ksS + 8] = pk.s[1];
    }
    __syncthreads();

    f32x4 acc[8] = {};

    for (int jt = 0; jt < 16; ++jt) {
        int cur = jt & 1;
        float4 q0, q1, q2, q3;
        if (jt < 15) {
            const float* src = h2 + (size_t)cS * 1024 + 512 + (jt + 1) * 32 + ksS;
            q0 = *(const float4*)(src + 0);
            q1 = *(const float4*)(src + 4);
            q2 = *(const float4*)(src + 8);
            q3 = *(const float4*)(src + 12);
        }
        int j0 = jt * 32 + g * 8;
        float p[8];
        #pragma unroll
        for (int qq = 0; qq < 8; ++qq) {
            float tq = fv + f2s[j0 + qq];
            float ev = fmaxf(tq, ALPHA * tq);
            p[qq] = __expf(ev - mr);
            zacc += p[qq];
        }
        union { unsigned u[4]; short8 s; } pfu;
        pfu.u[0] = packbf(p[0], p[1]);
        pfu.u[1] = packbf(p[2], p[3]);
        pfu.u[2] = packbf(p[4], p[5]);
        pfu.u[3] = packbf(p[6], p[7]);
        short8 pf = pfu.s;
        #pragma unroll
        for (int ct = 0; ct < 8; ++ct) {
            short8 hf = *(const short8*)&hbuf[cur][ct * 16 + l15][g * 8];
            acc[ct] = __builtin_amdgcn_mfma_f32_16x16x32_bf16(hf, pf, acc[ct], 0, 0, 0);
        }
        if (jt < 15) {
            union { unsigned u[8]; short8 s[2]; } pk;
            pk.u[0] = packbf_rne(q0.x, q0.y); pk.u[1] = packbf_rne(q0.z, q0.w);
            pk.u[2] = packbf_rne(q1.x, q1.y); pk.u[3] = packbf_rne(q1.z, q1.w);
            pk.u[4] = packbf_rne(q2.x, q2.y); pk.u[5] = packbf_rne(q2.z, q2.w);
            pk.u[6] = packbf_rne(q3.x, q3.y); pk.u[7] = packbf_rne(q3.z, q3.w);
            *(short8*)&hbuf[cur ^ 1][cS][ksS] = pk.s[0];
            *(short8*)&hbuf[cur ^ 1][cS][ksS + 8] = pk.s[1];
        }
        __syncthreads();
    }

    // self-loop diagonal MFMA, fragments from h2acc f32
    {
        unsigned short z0b = f2b(z0);
        short8 pfs;
        #pragma unroll
        for (int qq = 0; qq < 8; ++qq)
            pfs[qq] = (short)((g * 8 + qq == l15) ? z0b : 0);
        #pragma unroll
        for (int ct = 0; ct < 8; ++ct) {
            const float* src = h2 + (size_t)(ct * 16 + l15) * 1024 + i0 + g * 8;
            float4 q0 = *(const float4*)(src + 0);
            float4 q1 = *(const float4*)(src + 4);
            union { unsigned u[4]; short8 s; } pk;
            pk.u[0] = packbf_rne(q0.x, q0.y); pk.u[1] = packbf_rne(q0.z, q0.w);
            pk.u[2] = packbf_rne(q1.x, q1.y); pk.u[3] = packbf_rne(q1.z, q1.w);
            acc[ct] = __builtin_amdgcn_mfma_f32_16x16x32_bf16(pk.s, pfs, acc[ct], 0, 0, 0);
        }
    }

    zacc += __shfl_xor(zacc, 16, 64);
    zacc += __shfl_xor(zacc, 32, 64);
    float zinv = 1.f / zacc;

    float o[8][4];
    float mx = -3.0e38f;
    #pragma unroll
    for (int ct = 0; ct < 8; ++ct) {
        #pragma unroll
        for (int r = 0; r < 4; ++r) {
            float v = acc[ct][r] * zinv;
            v = v > 0.f ? v : __expf(v) - 1.f;
            o[ct][r] = v;
            mx = fmaxf(mx, v);
        }
    }
    mx = fmaxf(mx, __shfl_xor(mx, 16, 64));
    mx = fmaxf(mx, __shfl_xor(mx, 32, 64));
    float s = 0.f;
    #pragma unroll
    for (int ct = 0; ct < 8; ++ct)
        #pragma unroll
        for (int r = 0; r < 4; ++r) s += __expf(o[ct][r] - mx);
    s += __shfl_xor(s, 16, 64);
    s += __shfl_xor(s, 32, 64);
    float lse = mx + __logf(s);
    #pragma unroll
    for (int ct = 0; ct < 8; ++ct) {
        float4 st = {o[ct][0] - lse, o[ct][1] - lse, o[ct][2] - lse, o[ct][3] - lse};
        *(float4*)&dout[((size_t)(b * 512 + i)) * 128 + ct * 16 + g * 4] = st;
    }
}

extern "C" void kernel_launch(void* const* d_in, const int* in_sizes, int n_in,
                              void* d_out, int out_size, void* d_ws, size_t ws_size,
                              hipStream_t stream)
{
    const float* hs = (const float*)d_in[0];
    const float* os = (const float*)d_in[1];
    const float* Wh = (const float*)d_in[4];
    const float* ah = (const float*)d_in[5];
    const float* Wo = (const float*)d_in[6];
    const float* ao = (const float*)d_in[7];
    float* out = (float*)d_out;

    u16t* h1T = (u16t*)d_ws;              // 4,194,304 u16
    u16t* WoT = h1T + 4194304;            // 65,536 u16
    float* h2acc = (float*)(WoT + 65536); // 1,048,576 f32
    float* f1a = h2acc + 1048576;         // 32,768 f32
    float* f2a = f1a + 32768;             // 32,768 f32
    float* f1b = f2a + 32768;             // 8,192 f32
    float* f2b_ = f1b + 8192;             // 8,192 f32 (contiguous with f1b)

    proj1_kernel<<<256, 512, 0, stream>>>(hs, os, Wh, Wo, ah, h1T, WoT,
                                          f1a, f2a, h2acc, f1b);
    attn0_kernel<<<512, 256, 0, stream>>>(h1T, f1a, f2a, WoT, ao,
                                          h2acc, f1b, f2b_);
    attn1_kernel<<<64, 256, 0, stream>>>(h2acc, f1b, f2b_, out);
}

// Round 13
// 51.738 us; speedup vs baseline: 6.2496x; 1.2502x over previous
//
#include <hip/hip_runtime.h>

#define B 8
#define NH 512
#define D 128
#define HEADS 4
#define ALPHA 0.2f

typedef short short8 __attribute__((ext_vector_type(8)));
typedef float f32x4 __attribute__((ext_vector_type(4)));
typedef unsigned short u16t;

__device__ __forceinline__ unsigned short f2b(float f) {
    union { float f; unsigned u; } v; v.f = f;
    unsigned r = v.u + 0x7FFFu + ((v.u >> 16) & 1u);
    return (unsigned short)(r >> 16);
}
__device__ __forceinline__ float lrelu(float x) { return fmaxf(x, ALPHA * x); }
// pack two f32 -> two bf16 (truncation) in one v_perm
__device__ __forceinline__ unsigned packbf(float a, float b) {
    union { float f; unsigned u; } ua, ub; ua.f = a; ub.f = b;
    return __builtin_amdgcn_perm(ub.u, ua.u, 0x07060302u);
}
// pack two f32 -> two bf16 with RNE rounding (matches f2b)
__device__ __forceinline__ unsigned packbf_rne(float a, float b) {
    return (unsigned)f2b(a) | ((unsigned)f2b(b) << 16);
}
__device__ __forceinline__ unsigned long long pack4_rne(f32x4 v) {
    return (unsigned long long)packbf_rne(v[0], v[1])
         | ((unsigned long long)packbf_rne(v[2], v[3]) << 32);
}

// ============ proj1: h1T[bh][c][n] = (x @ Wh)^T, + f1a/f2a =================
// grid 256 (64 row-tiles of 128 x 4 heads), 512 thr (r9 proven version).
// Side-job: bid<64 emit WoT[c][k]=bf16(Wo[k][c]).
__global__ __launch_bounds__(512) void proj1_kernel(
    const float* __restrict__ hs, const float* __restrict__ os,
    const float* __restrict__ Wh, const float* __restrict__ Wo,
    const float* __restrict__ ah,
    u16t* __restrict__ h1T, u16t* __restrict__ WoT,
    float* __restrict__ f1, float* __restrict__ f2)
{
    int bid = blockIdx.x;
    int rt = bid >> 2, h = bid & 3;
    int rowG = rt * 128;
    int b = rowG >> 10;
    int t = threadIdx.x;
    int w = t >> 6, l = t & 63, l15 = l & 15, g = l >> 4;

    __shared__ __align__(16) u16t wlds[128][136];   // [c][k], pad 8

    // stage W[h]^T into LDS: 8192 pairs / 512 thr = 16 iters
    {
        const float* Whh = Wh + (size_t)h * 16384;
        #pragma unroll
        for (int i = 0; i < 16; ++i) {
            int p = i * 512 + t;
            int c = p & 127, k0 = (p >> 7) * 2;
            float w0 = Whh[(size_t)k0 * 128 + c];
            float w1 = Whh[(size_t)(k0 + 1) * 128 + c];
            *(unsigned*)&wlds[c][k0] = packbf_rne(w0, w1);
        }
    }
    // side job: emit WoT (64 blocks x 512 thr x 2 elems = 65536)
    if (bid < 64) {
        int idx = bid * 1024 + t * 2;
        int c = idx >> 9, k = idx & 511;
        float w0 = Wo[(size_t)k * 128 + c];
        float w1 = Wo[(size_t)(k + 1) * 128 + c];
        *(unsigned*)&WoT[(size_t)c * 512 + k] = packbf_rne(w0, w1);
    }
    __syncthreads();

    int nA = rowG + w * 16 + l15;
    int nloc = nA & 1023;
    const float* xr = (nloc < NH) ? hs + ((size_t)(b * NH + nloc)) * 128
                                  : os + ((size_t)(b * NH + (nloc - NH))) * 128;

    f32x4 acc[8] = {};
    #pragma unroll
    for (int kc = 0; kc < 4; ++kc) {
        int k0 = kc * 32 + g * 8;
        float4 u0 = *(const float4*)&xr[k0];
        float4 u1 = *(const float4*)&xr[k0 + 4];
        union { unsigned u[4]; short8 s; } afu;
        afu.u[0] = packbf_rne(u0.x, u0.y);
        afu.u[1] = packbf_rne(u0.z, u0.w);
        afu.u[2] = packbf_rne(u1.x, u1.y);
        afu.u[3] = packbf_rne(u1.z, u1.w);
        short8 af = afu.s;
        #pragma unroll
        for (int ct = 0; ct < 8; ++ct) {
            short8 bfr = *(const short8*)&wlds[ct * 16 + l15][k0];
            acc[ct] = __builtin_amdgcn_mfma_f32_16x16x32_bf16(af, bfr, acc[ct], 0, 0, 0);
        }
    }

    int bh = b * HEADS + h;
    size_t hTbase = (size_t)bh * 131072;
    int nloc0 = (rowG & 1023) + w * 16 + g * 4;
    float pr1[4] = {0.f, 0.f, 0.f, 0.f}, pr2[4] = {0.f, 0.f, 0.f, 0.f};

    #pragma unroll
    for (int ct = 0; ct < 8; ++ct) {
        int c = ct * 16 + l15;
        *(unsigned long long*)&h1T[hTbase + (size_t)c * 1024 + nloc0] = pack4_rne(acc[ct]);
        float a1 = ah[h * 256 + c], a2 = ah[h * 256 + 128 + c];
        #pragma unroll
        for (int r = 0; r < 4; ++r) {
            pr1[r] = fmaf(acc[ct][r], a1, pr1[r]);
            pr2[r] = fmaf(acc[ct][r], a2, pr2[r]);
        }
    }
    #pragma unroll
    for (int r = 0; r < 4; ++r) {
        float v1 = pr1[r], v2 = pr2[r];
        #pragma unroll
        for (int m = 1; m <= 8; m <<= 1) {
            v1 += __shfl_xor(v1, m, 64);
            v2 += __shfl_xor(v2, m, 64);
        }
        if (l15 == 0) {
            f1[(size_t)bh * 1024 + nloc0 + r] = v1;
            f2[(size_t)bh * 1024 + nloc0 + r] = v2;
        }
    }
}

// ============ attn0: x2 = elu(softmax(e) @ H) per head, bf16 ===============
// 512 blocks (XCD-swizzled), r9 proven version.
__global__ __launch_bounds__(256) void attn0_kernel(
    const u16t* __restrict__ HT,                    // [Z][128][1024] bf16
    const float* __restrict__ f1, const float* __restrict__ f2,  // [Z][1024]
    u16t* __restrict__ x2)                          // [8192][512] bf16
{
    __shared__ __align__(16) u16t hbuf[2][128][40];
    __shared__ __align__(16) float f2s[512];
    __shared__ float red4[4];

    int t = threadIdx.x, w4 = t >> 6, l = t & 63, l15 = l & 15, g = l >> 4;
    int wid = blockIdx.x;
    int xcd = wid & 7, jj = (wid >> 3) & 7;
    int itile = wid >> 6;
    int q = xcd * 8 + jj;
    int z = q >> 1, side = q & 1;
    int b = z >> 2, h = z & 3;
    bool self = (side == 0);
    int nbBase = self ? 512 : 0;
    size_t HTbase = (size_t)z * 131072;
    size_t fbase = (size_t)z * 1024;

    f2s[t] = f2[fbase + nbBase + t];
    f2s[t + 256] = f2[fbase + nbBase + t + 256];
    __syncthreads();
    float mv = fmaxf(f2s[t], f2s[t + 256]);
    #pragma unroll
    for (int m = 1; m <= 32; m <<= 1) mv = fmaxf(mv, __shfl_xor(mv, m, 64));
    if (l == 0) red4[w4] = mv;
    __syncthreads();
    float M = fmaxf(fmaxf(red4[0], red4[1]), fmaxf(red4[2], red4[3]));

    int i0 = itile * 64 + w4 * 16;
    int i = i0 + l15;
    int n = side * 512 + i;
    float fv = f1[fbase + n];
    float mr = lrelu(fv + M);
    float z0 = 0.f;
    if (self) {
        float sc = lrelu(fv + f2[fbase + i]);
        mr = fmaxf(mr, sc);
        z0 = __expf(sc - mr);
    }
    float zacc = (g == 0) ? z0 : 0.f;

    {
        int c = t >> 1, ks = (t & 1) * 16;
        const u16t* src = &HT[HTbase + (size_t)c * 1024 + nbBase + ks];
        *(short8*)&hbuf[0][c][ks] = *(const short8*)src;
        *(short8*)&hbuf[0][c][ks + 8] = *(const short8*)(src + 8);
    }
    __syncthreads();

    f32x4 acc[8] = {};
    int cS = t >> 1, ksS = (t & 1) * 16;

    for (int jt = 0; jt < 16; ++jt) {
        int cur = jt & 1;
        short8 s0, s1;
        if (jt < 15) {
            const u16t* src = &HT[HTbase + (size_t)cS * 1024 + nbBase + (jt + 1) * 32 + ksS];
            s0 = *(const short8*)src;
            s1 = *(const short8*)(src + 8);
        }
        int j0 = jt * 32 + g * 8;
        float p[8];
        #pragma unroll
        for (int qq = 0; qq < 8; ++qq) {
            float tq = fv + f2s[j0 + qq];
            float ev = fmaxf(tq, ALPHA * tq);
            p[qq] = __expf(ev - mr);
            zacc += p[qq];
        }
        union { unsigned u[4]; short8 s; } pfu;
        pfu.u[0] = packbf(p[0], p[1]);
        pfu.u[1] = packbf(p[2], p[3]);
        pfu.u[2] = packbf(p[4], p[5]);
        pfu.u[3] = packbf(p[6], p[7]);
        short8 pf = pfu.s;
        #pragma unroll
        for (int ct = 0; ct < 8; ++ct) {
            short8 hf = *(const short8*)&hbuf[cur][ct * 16 + l15][g * 8];
            acc[ct] = __builtin_amdgcn_mfma_f32_16x16x32_bf16(hf, pf, acc[ct], 0, 0, 0);
        }
        if (jt < 15) {
            *(short8*)&hbuf[cur ^ 1][cS][ksS] = s0;
            *(short8*)&hbuf[cur ^ 1][cS][ksS + 8] = s1;
        }
        __syncthreads();
    }

    // self-loop via diagonal-B MFMA
    if (self) {
        unsigned short z0b = f2b(z0);
        short8 pfs;
        #pragma unroll
        for (int qq = 0; qq < 8; ++qq)
            pfs[qq] = (short)((g * 8 + qq == l15) ? z0b : 0);
        int sc0 = side * 512 + i0;
        #pragma unroll
        for (int ct = 0; ct < 8; ++ct) {
            short8 hfs = *(const short8*)&HT[HTbase + (size_t)(ct * 16 + l15) * 1024 + sc0 + g * 8];
            acc[ct] = __builtin_amdgcn_mfma_f32_16x16x32_bf16(hfs, pfs, acc[ct], 0, 0, 0);
        }
    }

    zacc += __shfl_xor(zacc, 16, 64);
    zacc += __shfl_xor(zacc, 32, 64);
    float zinv = 1.f / zacc;

    size_t orow = ((size_t)(b * 1024 + n)) * 512 + h * 128;
    #pragma unroll
    for (int ct = 0; ct < 8; ++ct) {
        int c0 = ct * 16 + g * 4;
        float o[4];
        #pragma unroll
        for (int r = 0; r < 4; ++r) {
            float v = acc[ct][r] * zinv;
            o[r] = v > 0.f ? v : __expf(v) - 1.f;
        }
        unsigned long long pv =
              (unsigned long long)packbf_rne(o[0], o[1])
            | ((unsigned long long)packbf_rne(o[2], o[3]) << 32);
        *(unsigned long long*)&x2[orow + c0] = pv;
    }
}

// ============ proj2: h2T = (x2 @ Wo)^T, ct-split, + f-partials =============
// grid 256 (128 row-tiles of 64 x 2 ct-halves), 256 thr.
// Each block: 64 rows x 64 features. f1/f2 dots -> per-half partial buffers.
__global__ __launch_bounds__(256) void proj2_kernel(
    const u16t* __restrict__ x2, const u16t* __restrict__ WoT,
    const float* __restrict__ ao,
    u16t* __restrict__ h2T, float* __restrict__ f1p, float* __restrict__ f2p)
{
    int bid = blockIdx.x;
    int rowG = (bid >> 1) * 64;
    int half = bid & 1;
    int b = rowG >> 10;
    int t = threadIdx.x;
    int w = t >> 6, l = t & 63, l15 = l & 15, g = l >> 4;

    int rowA = rowG + w * 16 + l15;

    f32x4 acc[4] = {};
    #pragma unroll
    for (int kc = 0; kc < 16; ++kc) {
        int k0 = kc * 32 + g * 8;
        short8 af = *(const short8*)&x2[(size_t)rowA * 512 + k0];
        #pragma unroll
        for (int ctl = 0; ctl < 4; ++ctl) {
            int c = (half * 4 + ctl) * 16 + l15;
            short8 bfr = *(const short8*)&WoT[(size_t)c * 512 + k0];
            acc[ctl] = __builtin_amdgcn_mfma_f32_16x16x32_bf16(af, bfr, acc[ctl], 0, 0, 0);
        }
    }

    size_t hTbase = (size_t)b * 131072;
    int nloc0 = (rowG & 1023) + w * 16 + g * 4;
    int rowOut0 = rowG + w * 16 + g * 4;
    float pr1[4] = {0.f, 0.f, 0.f, 0.f}, pr2[4] = {0.f, 0.f, 0.f, 0.f};

    #pragma unroll
    for (int ctl = 0; ctl < 4; ++ctl) {
        int c = (half * 4 + ctl) * 16 + l15;
        *(unsigned long long*)&h2T[hTbase + (size_t)c * 1024 + nloc0] = pack4_rne(acc[ctl]);
        float a1 = ao[c], a2 = ao[128 + c];
        #pragma unroll
        for (int r = 0; r < 4; ++r) {
            pr1[r] = fmaf(acc[ctl][r], a1, pr1[r]);
            pr2[r] = fmaf(acc[ctl][r], a2, pr2[r]);
        }
    }
    #pragma unroll
    for (int r = 0; r < 4; ++r) {
        float v1 = pr1[r], v2 = pr2[r];
        #pragma unroll
        for (int m = 1; m <= 8; m <<= 1) {
            v1 += __shfl_xor(v1, m, 64);
            v2 += __shfl_xor(v2, m, 64);
        }
        if (l15 == 0) {
            f1p[half * 8192 + rowOut0 + r] = v1;
            f2p[half * 8192 + rowOut0 + r] = v2;
        }
    }
}

// ============ attn1: layer-2 attention, ct split across waves ==============
// grid 256 (8 b x 32 itiles of 16 rows), 256 thr. Each wave: same 16 rows,
// 2 of 8 ct tiles. Fused elu + log_softmax (cross-wave LDS reduce).
__global__ __launch_bounds__(256) void attn1_kernel(
    const u16t* __restrict__ HT,                    // h2T [B][128][1024] bf16
    const float* __restrict__ f1p, const float* __restrict__ f2p, // [2][8192]
    float* __restrict__ dout)
{
    __shared__ __align__(16) u16t hbuf[2][128][40];
    __shared__ __align__(16) float f2s[512];
    __shared__ float red4[4];
    __shared__ float mxw[4][16], sw[4][16];

    int t = threadIdx.x, w4 = t >> 6, l = t & 63, l15 = l & 15, g = l >> 4;
    int b = blockIdx.x & 7, itile = blockIdx.x >> 3;
    size_t HTbase = (size_t)b * 131072;
    int fb = b * 1024;

    f2s[t] = f2p[fb + 512 + t] + f2p[8192 + fb + 512 + t];
    f2s[t + 256] = f2p[fb + 768 + t] + f2p[8192 + fb + 768 + t];
    __syncthreads();
    float mv = fmaxf(f2s[t], f2s[t + 256]);
    #pragma unroll
    for (int m = 1; m <= 32; m <<= 1) mv = fmaxf(mv, __shfl_xor(mv, m, 64));
    if (l == 0) red4[w4] = mv;
    __syncthreads();
    float M = fmaxf(fmaxf(red4[0], red4[1]), fmaxf(red4[2], red4[3]));

    int i0 = itile * 16;
    int i = i0 + l15;
    float fv = f1p[fb + i] + f1p[8192 + fb + i];
    float f2self = f2p[fb + i] + f2p[8192 + fb + i];
    float mr = lrelu(fv + M);
    float sc = lrelu(fv + f2self);
    mr = fmaxf(mr, sc);
    float z0 = __expf(sc - mr);
    float zacc = (g == 0) ? z0 : 0.f;

    int ct0 = w4 * 2, ct1 = w4 * 2 + 1;

    // prologue: stage chunk 0
    int cS = t >> 1, ksS = (t & 1) * 16;
    {
        const u16t* src = &HT[HTbase + (size_t)cS * 1024 + 512 + ksS];
        *(short8*)&hbuf[0][cS][ksS] = *(const short8*)src;
        *(short8*)&hbuf[0][cS][ksS + 8] = *(const short8*)(src + 8);
    }
    __syncthreads();

    f32x4 acc[2] = {};

    for (int jt = 0; jt < 16; ++jt) {
        int cur = jt & 1;
        short8 s0, s1;
        if (jt < 15) {
            const u16t* src = &HT[HTbase + (size_t)cS * 1024 + 512 + (jt + 1) * 32 + ksS];
            s0 = *(const short8*)src;
            s1 = *(const short8*)(src + 8);
        }
        int j0 = jt * 32 + g * 8;
        float p[8];
        #pragma unroll
        for (int qq = 0; qq < 8; ++qq) {
            float tq = fv + f2s[j0 + qq];
            float ev = fmaxf(tq, ALPHA * tq);
            p[qq] = __expf(ev - mr);
            zacc += p[qq];
        }
        union { unsigned u[4]; short8 s; } pfu;
        pfu.u[0] = packbf(p[0], p[1]);
        pfu.u[1] = packbf(p[2], p[3]);
        pfu.u[2] = packbf(p[4], p[5]);
        pfu.u[3] = packbf(p[6], p[7]);
        short8 pf = pfu.s;
        {
            short8 hf0 = *(const short8*)&hbuf[cur][ct0 * 16 + l15][g * 8];
            acc[0] = __builtin_amdgcn_mfma_f32_16x16x32_bf16(hf0, pf, acc[0], 0, 0, 0);
            short8 hf1 = *(const short8*)&hbuf[cur][ct1 * 16 + l15][g * 8];
            acc[1] = __builtin_amdgcn_mfma_f32_16x16x32_bf16(hf1, pf, acc[1], 0, 0, 0);
        }
        if (jt < 15) {
            *(short8*)&hbuf[cur ^ 1][cS][ksS] = s0;
            *(short8*)&hbuf[cur ^ 1][cS][ksS + 8] = s1;
        }
        __syncthreads();
    }

    // self-loop via diagonal-B MFMA (self columns = humans i0..i0+15)
    {
        unsigned short z0b = f2b(z0);
        short8 pfs;
        #pragma unroll
        for (int qq = 0; qq < 8; ++qq)
            pfs[qq] = (short)((g * 8 + qq == l15) ? z0b : 0);
        short8 hfs0 = *(const short8*)&HT[HTbase + (size_t)(ct0 * 16 + l15) * 1024 + i0 + g * 8];
        acc[0] = __builtin_amdgcn_mfma_f32_16x16x32_bf16(hfs0, pfs, acc[0], 0, 0, 0);
        short8 hfs1 = *(const short8*)&HT[HTbase + (size_t)(ct1 * 16 + l15) * 1024 + i0 + g * 8];
        acc[1] = __builtin_amdgcn_mfma_f32_16x16x32_bf16(hfs1, pfs, acc[1], 0, 0, 0);
    }

    zacc += __shfl_xor(zacc, 16, 64);
    zacc += __shfl_xor(zacc, 32, 64);
    float zinv = 1.f / zacc;

    // elu + per-wave partial max over this wave's 32 features
    float o[2][4];
    float mx = -3.0e38f;
    #pragma unroll
    for (int ctl = 0; ctl < 2; ++ctl) {
        #pragma unroll
        for (int r = 0; r < 4; ++r) {
            float v = acc[ctl][r] * zinv;
            v = v > 0.f ? v : __expf(v) - 1.f;
            o[ctl][r] = v;
            mx = fmaxf(mx, v);
        }
    }
    mx = fmaxf(mx, __shfl_xor(mx, 16, 64));
    mx = fmaxf(mx, __shfl_xor(mx, 32, 64));
    if (l < 16) mxw[w4][l] = mx;
    __syncthreads();
    float mxf = fmaxf(fmaxf(mxw[0][l15], mxw[1][l15]),
                      fmaxf(mxw[2][l15], mxw[3][l15]));
    float s = 0.f;
    #pragma unroll
    for (int ctl = 0; ctl < 2; ++ctl)
        #pragma unroll
        for (int r = 0; r < 4; ++r) s += __expf(o[ctl][r] - mxf);
    s += __shfl_xor(s, 16, 64);
    s += __shfl_xor(s, 32, 64);
    if (l < 16) sw[w4][l] = s;
    __syncthreads();
    float sf = sw[0][l15] + sw[1][l15] + sw[2][l15] + sw[3][l15];
    float lse = mxf + __logf(sf);

    #pragma unroll
    for (int ctl = 0; ctl < 2; ++ctl) {
        int ct = w4 * 2 + ctl;
        float4 st = {o[ctl][0] - lse, o[ctl][1] - lse,
                     o[ctl][2] - lse, o[ctl][3] - lse};
        *(float4*)&dout[((size_t)(b * 512 + i)) * 128 + ct * 16 + g * 4] = st;
    }
}

extern "C" void kernel_launch(void* const* d_in, const int* in_sizes, int n_in,
                              void* d_out, int out_size, void* d_ws, size_t ws_size,
                              hipStream_t stream)
{
    const float* hs = (const float*)d_in[0];
    const float* os = (const float*)d_in[1];
    const float* Wh = (const float*)d_in[4];
    const float* ah = (const float*)d_in[5];
    const float* Wo = (const float*)d_in[6];
    const float* ao = (const float*)d_in[7];
    float* out = (float*)d_out;

    u16t* h1T = (u16t*)d_ws;             // 4,194,304 u16
    u16t* x2  = h1T + 4194304;           // 4,194,304 u16
    u16t* h2T = x2 + 4194304;            // 1,048,576 u16
    u16t* WoT = h2T + 1048576;           // 65,536 u16
    float* f1a = (float*)(WoT + 65536);  // 32,768 f32
    float* f2a = f1a + 32768;
    float* f1p = f2a + 32768;            // 16,384 f32 (2 halves x 8192)
    float* f2p = f1p + 16384;            // 16,384 f32

    proj1_kernel<<<256, 512, 0, stream>>>(hs, os, Wh, Wo, ah, h1T, WoT, f1a, f2a);
    attn0_kernel<<<512, 256, 0, stream>>>(h1T, f1a, f2a, x2);
    proj2_kernel<<<256, 256, 0, stream>>>(x2, WoT, ao, h2T, f1p, f2p);
    attn1_kernel<<<256, 256, 0, stream>>>(h2T, f1p, f2p, out);
}

// Round 14
// 49.550 us; speedup vs baseline: 6.5255x; 1.0441x over previous
//
#include <hip/hip_runtime.h>

#define B 8
#define NH 512
#define D 128
#define HEADS 4
#define ALPHA 0.2f

typedef short short8 __attribute__((ext_vector_type(8)));
typedef float f32x4 __attribute__((ext_vector_type(4)));
typedef unsigned short u16t;

__device__ __forceinline__ unsigned short f2b(float f) {
    union { float f; unsigned u; } v; v.f = f;
    unsigned r = v.u + 0x7FFFu + ((v.u >> 16) & 1u);
    return (unsigned short)(r >> 16);
}
__device__ __forceinline__ float lrelu(float x) { return fmaxf(x, ALPHA * x); }
// pack two f32 -> two bf16 (truncation) in one v_perm
__device__ __forceinline__ unsigned packbf(float a, float b) {
    union { float f; unsigned u; } ua, ub; ua.f = a; ub.f = b;
    return __builtin_amdgcn_perm(ub.u, ua.u, 0x07060302u);
}
// pack two f32 -> two bf16 with RNE rounding (matches f2b)
__device__ __forceinline__ unsigned packbf_rne(float a, float b) {
    return (unsigned)f2b(a) | ((unsigned)f2b(b) << 16);
}
__device__ __forceinline__ unsigned long long pack4_rne(f32x4 v) {
    return (unsigned long long)packbf_rne(v[0], v[1])
         | ((unsigned long long)packbf_rne(v[2], v[3]) << 32);
}

// ============ proj1: h1T[bh][c][n] = (x @ Wh)^T, + f1a/f2a =================
// grid 256 (64 row-tiles of 128 x 4 heads), 512 thr (r9/r13 proven).
// Side-job: bid<64 emit WoT[c][k]=bf16(Wo[k][c]).
__global__ __launch_bounds__(512) void proj1_kernel(
    const float* __restrict__ hs, const float* __restrict__ os,
    const float* __restrict__ Wh, const float* __restrict__ Wo,
    const float* __restrict__ ah,
    u16t* __restrict__ h1T, u16t* __restrict__ WoT,
    float* __restrict__ f1, float* __restrict__ f2)
{
    int bid = blockIdx.x;
    int rt = bid >> 2, h = bid & 3;
    int rowG = rt * 128;
    int b = rowG >> 10;
    int t = threadIdx.x;
    int w = t >> 6, l = t & 63, l15 = l & 15, g = l >> 4;

    __shared__ __align__(16) u16t wlds[128][136];   // [c][k], pad 8

    // stage W[h]^T into LDS: 8192 pairs / 512 thr = 16 iters
    {
        const float* Whh = Wh + (size_t)h * 16384;
        #pragma unroll
        for (int i = 0; i < 16; ++i) {
            int p = i * 512 + t;
            int c = p & 127, k0 = (p >> 7) * 2;
            float w0 = Whh[(size_t)k0 * 128 + c];
            float w1 = Whh[(size_t)(k0 + 1) * 128 + c];
            *(unsigned*)&wlds[c][k0] = packbf_rne(w0, w1);
        }
    }
    // side job: emit WoT (64 blocks x 512 thr x 2 elems = 65536)
    if (bid < 64) {
        int idx = bid * 1024 + t * 2;
        int c = idx >> 9, k = idx & 511;
        float w0 = Wo[(size_t)k * 128 + c];
        float w1 = Wo[(size_t)(k + 1) * 128 + c];
        *(unsigned*)&WoT[(size_t)c * 512 + k] = packbf_rne(w0, w1);
    }
    __syncthreads();

    int nA = rowG + w * 16 + l15;
    int nloc = nA & 1023;
    const float* xr = (nloc < NH) ? hs + ((size_t)(b * NH + nloc)) * 128
                                  : os + ((size_t)(b * NH + (nloc - NH))) * 128;

    f32x4 acc[8] = {};
    #pragma unroll
    for (int kc = 0; kc < 4; ++kc) {
        int k0 = kc * 32 + g * 8;
        float4 u0 = *(const float4*)&xr[k0];
        float4 u1 = *(const float4*)&xr[k0 + 4];
        union { unsigned u[4]; short8 s; } afu;
        afu.u[0] = packbf_rne(u0.x, u0.y);
        afu.u[1] = packbf_rne(u0.z, u0.w);
        afu.u[2] = packbf_rne(u1.x, u1.y);
        afu.u[3] = packbf_rne(u1.z, u1.w);
        short8 af = afu.s;
        #pragma unroll
        for (int ct = 0; ct < 8; ++ct) {
            short8 bfr = *(const short8*)&wlds[ct * 16 + l15][k0];
            acc[ct] = __builtin_amdgcn_mfma_f32_16x16x32_bf16(af, bfr, acc[ct], 0, 0, 0);
        }
    }

    int bh = b * HEADS + h;
    size_t hTbase = (size_t)bh * 131072;
    int nloc0 = (rowG & 1023) + w * 16 + g * 4;
    float pr1[4] = {0.f, 0.f, 0.f, 0.f}, pr2[4] = {0.f, 0.f, 0.f, 0.f};

    #pragma unroll
    for (int ct = 0; ct < 8; ++ct) {
        int c = ct * 16 + l15;
        *(unsigned long long*)&h1T[hTbase + (size_t)c * 1024 + nloc0] = pack4_rne(acc[ct]);
        float a1 = ah[h * 256 + c], a2 = ah[h * 256 + 128 + c];
        #pragma unroll
        for (int r = 0; r < 4; ++r) {
            pr1[r] = fmaf(acc[ct][r], a1, pr1[r]);
            pr2[r] = fmaf(acc[ct][r], a2, pr2[r]);
        }
    }
    #pragma unroll
    for (int r = 0; r < 4; ++r) {
        float v1 = pr1[r], v2 = pr2[r];
        #pragma unroll
        for (int m = 1; m <= 8; m <<= 1) {
            v1 += __shfl_xor(v1, m, 64);
            v2 += __shfl_xor(v2, m, 64);
        }
        if (l15 == 0) {
            f1[(size_t)bh * 1024 + nloc0 + r] = v1;
            f2[(size_t)bh * 1024 + nloc0 + r] = v2;
        }
    }
}

// ============ attn0: x2 = elu(softmax(e) @ H) per head, bf16 ===============
// 512 blocks (XCD-swizzled). 64-col chunks: 8 iterations, 1 barrier each
// (halves barrier/drain count vs 32-col chunks).
__global__ __launch_bounds__(256) void attn0_kernel(
    const u16t* __restrict__ HT,                    // [Z][128][1024] bf16
    const float* __restrict__ f1, const float* __restrict__ f2,  // [Z][1024]
    u16t* __restrict__ x2)                          // [8192][512] bf16
{
    __shared__ __align__(16) u16t hbuf[2][128][72]; // [buf][c][64+pad8]
    __shared__ __align__(16) float f2s[512];
    __shared__ float red4[4];

    int t = threadIdx.x, w4 = t >> 6, l = t & 63, l15 = l & 15, g = l >> 4;
    int wid = blockIdx.x;
    int xcd = wid & 7, jj = (wid >> 3) & 7;
    int itile = wid >> 6;
    int q = xcd * 8 + jj;
    int z = q >> 1, side = q & 1;
    int b = z >> 2, h = z & 3;
    bool self = (side == 0);
    int nbBase = self ? 512 : 0;
    size_t HTbase = (size_t)z * 131072;
    size_t fbase = (size_t)z * 1024;

    f2s[t] = f2[fbase + nbBase + t];
    f2s[t + 256] = f2[fbase + nbBase + t + 256];
    __syncthreads();
    float mv = fmaxf(f2s[t], f2s[t + 256]);
    #pragma unroll
    for (int m = 1; m <= 32; m <<= 1) mv = fmaxf(mv, __shfl_xor(mv, m, 64));
    if (l == 0) red4[w4] = mv;
    __syncthreads();
    float M = fmaxf(fmaxf(red4[0], red4[1]), fmaxf(red4[2], red4[3]));

    int i0 = itile * 64 + w4 * 16;
    int i = i0 + l15;
    int n = side * 512 + i;
    float fv = f1[fbase + n];
    float mr = lrelu(fv + M);
    float z0 = 0.f;
    if (self) {
        float sc = lrelu(fv + f2[fbase + i]);
        mr = fmaxf(mr, sc);
        z0 = __expf(sc - mr);
    }
    float zacc = (g == 0) ? z0 : 0.f;

    // staging geometry: 2 threads per c-row, 32 cols (64B) each
    int cS = t >> 1, ksS = (t & 1) * 32;

    // prologue: stage chunk 0
    {
        const u16t* src = &HT[HTbase + (size_t)cS * 1024 + nbBase + ksS];
        *(short8*)&hbuf[0][cS][ksS]      = *(const short8*)src;
        *(short8*)&hbuf[0][cS][ksS + 8]  = *(const short8*)(src + 8);
        *(short8*)&hbuf[0][cS][ksS + 16] = *(const short8*)(src + 16);
        *(short8*)&hbuf[0][cS][ksS + 24] = *(const short8*)(src + 24);
    }
    __syncthreads();

    f32x4 acc[8] = {};

    for (int jt = 0; jt < 8; ++jt) {
        int cur = jt & 1;
        short8 s0, s1, s2, s3;
        if (jt < 7) {
            const u16t* src = &HT[HTbase + (size_t)cS * 1024 + nbBase + (jt + 1) * 64 + ksS];
            s0 = *(const short8*)src;
            s1 = *(const short8*)(src + 8);
            s2 = *(const short8*)(src + 16);
            s3 = *(const short8*)(src + 24);
        }
        #pragma unroll
        for (int sub = 0; sub < 2; ++sub) {
            int j0 = jt * 64 + sub * 32 + g * 8;
            float p[8];
            #pragma unroll
            for (int qq = 0; qq < 8; ++qq) {
                float tq = fv + f2s[j0 + qq];
                float ev = fmaxf(tq, ALPHA * tq);
                p[qq] = __expf(ev - mr);
                zacc += p[qq];
            }
            union { unsigned u[4]; short8 s; } pfu;
            pfu.u[0] = packbf(p[0], p[1]);
            pfu.u[1] = packbf(p[2], p[3]);
            pfu.u[2] = packbf(p[4], p[5]);
            pfu.u[3] = packbf(p[6], p[7]);
            short8 pf = pfu.s;
            #pragma unroll
            for (int ct = 0; ct < 8; ++ct) {
                short8 hf = *(const short8*)&hbuf[cur][ct * 16 + l15][sub * 32 + g * 8];
                acc[ct] = __builtin_amdgcn_mfma_f32_16x16x32_bf16(hf, pf, acc[ct], 0, 0, 0);
            }
        }
        if (jt < 7) {
            *(short8*)&hbuf[cur ^ 1][cS][ksS]      = s0;
            *(short8*)&hbuf[cur ^ 1][cS][ksS + 8]  = s1;
            *(short8*)&hbuf[cur ^ 1][cS][ksS + 16] = s2;
            *(short8*)&hbuf[cur ^ 1][cS][ksS + 24] = s3;
        }
        __syncthreads();
    }

    // self-loop via diagonal-B MFMA
    if (self) {
        unsigned short z0b = f2b(z0);
        short8 pfs;
        #pragma unroll
        for (int qq = 0; qq < 8; ++qq)
            pfs[qq] = (short)((g * 8 + qq == l15) ? z0b : 0);
        int sc0 = side * 512 + i0;
        #pragma unroll
        for (int ct = 0; ct < 8; ++ct) {
            short8 hfs = *(const short8*)&HT[HTbase + (size_t)(ct * 16 + l15) * 1024 + sc0 + g * 8];
            acc[ct] = __builtin_amdgcn_mfma_f32_16x16x32_bf16(hfs, pfs, acc[ct], 0, 0, 0);
        }
    }

    zacc += __shfl_xor(zacc, 16, 64);
    zacc += __shfl_xor(zacc, 32, 64);
    float zinv = 1.f / zacc;

    size_t orow = ((size_t)(b * 1024 + n)) * 512 + h * 128;
    #pragma unroll
    for (int ct = 0; ct < 8; ++ct) {
        int c0 = ct * 16 + g * 4;
        float o[4];
        #pragma unroll
        for (int r = 0; r < 4; ++r) {
            float v = acc[ct][r] * zinv;
            o[r] = v > 0.f ? v : __expf(v) - 1.f;
        }
        unsigned long long pv =
              (unsigned long long)packbf_rne(o[0], o[1])
            | ((unsigned long long)packbf_rne(o[2], o[3]) << 32);
        *(unsigned long long*)&x2[orow + c0] = pv;
    }
}

// ============ proj2: h2T = (x2 @ Wo)^T, ct-split, + f-partials =============
// grid 256 (128 row-tiles of 64 x 2 ct-halves), 256 thr (r13 proven).
__global__ __launch_bounds__(256) void proj2_kernel(
    const u16t* __restrict__ x2, const u16t* __restrict__ WoT,
    const float* __restrict__ ao,
    u16t* __restrict__ h2T, float* __restrict__ f1p, float* __restrict__ f2p)
{
    int bid = blockIdx.x;
    int rowG = (bid >> 1) * 64;
    int half = bid & 1;
    int b = rowG >> 10;
    int t = threadIdx.x;
    int w = t >> 6, l = t & 63, l15 = l & 15, g = l >> 4;

    int rowA = rowG + w * 16 + l15;

    f32x4 acc[4] = {};
    #pragma unroll
    for (int kc = 0; kc < 16; ++kc) {
        int k0 = kc * 32 + g * 8;
        short8 af = *(const short8*)&x2[(size_t)rowA * 512 + k0];
        #pragma unroll
        for (int ctl = 0; ctl < 4; ++ctl) {
            int c = (half * 4 + ctl) * 16 + l15;
            short8 bfr = *(const short8*)&WoT[(size_t)c * 512 + k0];
            acc[ctl] = __builtin_amdgcn_mfma_f32_16x16x32_bf16(af, bfr, acc[ctl], 0, 0, 0);
        }
    }

    size_t hTbase = (size_t)b * 131072;
    int nloc0 = (rowG & 1023) + w * 16 + g * 4;
    int rowOut0 = rowG + w * 16 + g * 4;
    float pr1[4] = {0.f, 0.f, 0.f, 0.f}, pr2[4] = {0.f, 0.f, 0.f, 0.f};

    #pragma unroll
    for (int ctl = 0; ctl < 4; ++ctl) {
        int c = (half * 4 + ctl) * 16 + l15;
        *(unsigned long long*)&h2T[hTbase + (size_t)c * 1024 + nloc0] = pack4_rne(acc[ctl]);
        float a1 = ao[c], a2 = ao[128 + c];
        #pragma unroll
        for (int r = 0; r < 4; ++r) {
            pr1[r] = fmaf(acc[ctl][r], a1, pr1[r]);
            pr2[r] = fmaf(acc[ctl][r], a2, pr2[r]);
        }
    }
    #pragma unroll
    for (int r = 0; r < 4; ++r) {
        float v1 = pr1[r], v2 = pr2[r];
        #pragma unroll
        for (int m = 1; m <= 8; m <<= 1) {
            v1 += __shfl_xor(v1, m, 64);
            v2 += __shfl_xor(v2, m, 64);
        }
        if (l15 == 0) {
            f1p[half * 8192 + rowOut0 + r] = v1;
            f2p[half * 8192 + rowOut0 + r] = v2;
        }
    }
}

// ============ attn1: layer-2 attention, ct split across waves ==============
// grid 256 (8 b x 32 itiles of 16 rows), 256 thr. 64-col chunks (8 iters).
__global__ __launch_bounds__(256) void attn1_kernel(
    const u16t* __restrict__ HT,                    // h2T [B][128][1024] bf16
    const float* __restrict__ f1p, const float* __restrict__ f2p, // [2][8192]
    float* __restrict__ dout)
{
    __shared__ __align__(16) u16t hbuf[2][128][72];
    __shared__ __align__(16) float f2s[512];
    __shared__ float red4[4];
    __shared__ float mxw[4][16], sw[4][16];

    int t = threadIdx.x, w4 = t >> 6, l = t & 63, l15 = l & 15, g = l >> 4;
    int b = blockIdx.x & 7, itile = blockIdx.x >> 3;
    size_t HTbase = (size_t)b * 131072;
    int fb = b * 1024;

    f2s[t] = f2p[fb + 512 + t] + f2p[8192 + fb + 512 + t];
    f2s[t + 256] = f2p[fb + 768 + t] + f2p[8192 + fb + 768 + t];
    __syncthreads();
    float mv = fmaxf(f2s[t], f2s[t + 256]);
    #pragma unroll
    for (int m = 1; m <= 32; m <<= 1) mv = fmaxf(mv, __shfl_xor(mv, m, 64));
    if (l == 0) red4[w4] = mv;
    __syncthreads();
    float M = fmaxf(fmaxf(red4[0], red4[1]), fmaxf(red4[2], red4[3]));

    int i0 = itile * 16;
    int i = i0 + l15;
    float fv = f1p[fb + i] + f1p[8192 + fb + i];
    float f2self = f2p[fb + i] + f2p[8192 + fb + i];
    float mr = lrelu(fv + M);
    float sc = lrelu(fv + f2self);
    mr = fmaxf(mr, sc);
    float z0 = __expf(sc - mr);
    float zacc = (g == 0) ? z0 : 0.f;

    int ct0 = w4 * 2, ct1 = w4 * 2 + 1;
    int cS = t >> 1, ksS = (t & 1) * 32;

    // prologue: stage chunk 0
    {
        const u16t* src = &HT[HTbase + (size_t)cS * 1024 + 512 + ksS];
        *(short8*)&hbuf[0][cS][ksS]      = *(const short8*)src;
        *(short8*)&hbuf[0][cS][ksS + 8]  = *(const short8*)(src + 8);
        *(short8*)&hbuf[0][cS][ksS + 16] = *(const short8*)(src + 16);
        *(short8*)&hbuf[0][cS][ksS + 24] = *(const short8*)(src + 24);
    }
    __syncthreads();

    f32x4 acc[2] = {};

    for (int jt = 0; jt < 8; ++jt) {
        int cur = jt & 1;
        short8 s0, s1, s2, s3;
        if (jt < 7) {
            const u16t* src = &HT[HTbase + (size_t)cS * 1024 + 512 + (jt + 1) * 64 + ksS];
            s0 = *(const short8*)src;
            s1 = *(const short8*)(src + 8);
            s2 = *(const short8*)(src + 16);
            s3 = *(const short8*)(src + 24);
        }
        #pragma unroll
        for (int sub = 0; sub < 2; ++sub) {
            int j0 = jt * 64 + sub * 32 + g * 8;
            float p[8];
            #pragma unroll
            for (int qq = 0; qq < 8; ++qq) {
                float tq = fv + f2s[j0 + qq];
                float ev = fmaxf(tq, ALPHA * tq);
                p[qq] = __expf(ev - mr);
                zacc += p[qq];
            }
            union { unsigned u[4]; short8 s; } pfu;
            pfu.u[0] = packbf(p[0], p[1]);
            pfu.u[1] = packbf(p[2], p[3]);
            pfu.u[2] = packbf(p[4], p[5]);
            pfu.u[3] = packbf(p[6], p[7]);
            short8 pf = pfu.s;
            short8 hf0 = *(const short8*)&hbuf[cur][ct0 * 16 + l15][sub * 32 + g * 8];
            acc[0] = __builtin_amdgcn_mfma_f32_16x16x32_bf16(hf0, pf, acc[0], 0, 0, 0);
            short8 hf1 = *(const short8*)&hbuf[cur][ct1 * 16 + l15][sub * 32 + g * 8];
            acc[1] = __builtin_amdgcn_mfma_f32_16x16x32_bf16(hf1, pf, acc[1], 0, 0, 0);
        }
        if (jt < 7) {
            *(short8*)&hbuf[cur ^ 1][cS][ksS]      = s0;
            *(short8*)&hbuf[cur ^ 1][cS][ksS + 8]  = s1;
            *(short8*)&hbuf[cur ^ 1][cS][ksS + 16] = s2;
            *(short8*)&hbuf[cur ^ 1][cS][ksS + 24] = s3;
        }
        __syncthreads();
    }

    // self-loop via diagonal-B MFMA (self columns = humans i0..i0+15)
    {
        unsigned short z0b = f2b(z0);
        short8 pfs;
        #pragma unroll
        for (int qq = 0; qq < 8; ++qq)
            pfs[qq] = (short)((g * 8 + qq == l15) ? z0b : 0);
        short8 hfs0 = *(const short8*)&HT[HTbase + (size_t)(ct0 * 16 + l15) * 1024 + i0 + g * 8];
        acc[0] = __builtin_amdgcn_mfma_f32_16x16x32_bf16(hfs0, pfs, acc[0], 0, 0, 0);
        short8 hfs1 = *(const short8*)&HT[HTbase + (size_t)(ct1 * 16 + l15) * 1024 + i0 + g * 8];
        acc[1] = __builtin_amdgcn_mfma_f32_16x16x32_bf16(hfs1, pfs, acc[1], 0, 0, 0);
    }

    zacc += __shfl_xor(zacc, 16, 64);
    zacc += __shfl_xor(zacc, 32, 64);
    float zinv = 1.f / zacc;

    // elu + per-wave partial max over this wave's 32 features
    float o[2][4];
    float mx = -3.0e38f;
    #pragma unroll
    for (int ctl = 0; ctl < 2; ++ctl) {
        #pragma unroll
        for (int r = 0; r < 4; ++r) {
            float v = acc[ctl][r] * zinv;
            v = v > 0.f ? v : __expf(v) - 1.f;
            o[ctl][r] = v;
            mx = fmaxf(mx, v);
        }
    }
    mx = fmaxf(mx, __shfl_xor(mx, 16, 64));
    mx = fmaxf(mx, __shfl_xor(mx, 32, 64));
    if (l < 16) mxw[w4][l] = mx;
    __syncthreads();
    float mxf = fmaxf(fmaxf(mxw[0][l15], mxw[1][l15]),
                      fmaxf(mxw[2][l15], mxw[3][l15]));
    float s = 0.f;
    #pragma unroll
    for (int ctl = 0; ctl < 2; ++ctl)
        #pragma unroll
        for (int r = 0; r < 4; ++r) s += __expf(o[ctl][r] - mxf);
    s += __shfl_xor(s, 16, 64);
    s += __shfl_xor(s, 32, 64);
    if (l < 16) sw[w4][l] = s;
    __syncthreads();
    float sf = sw[0][l15] + sw[1][l15] + sw[2][l15] + sw[3][l15];
    float lse = mxf + __logf(sf);

    #pragma unroll
    for (int ctl = 0; ctl < 2; ++ctl) {
        int ct = w4 * 2 + ctl;
        float4 st = {o[ctl][0] - lse, o[ctl][1] - lse,
                     o[ctl][2] - lse, o[ctl][3] - lse};
        *(float4*)&dout[((size_t)(b * 512 + i)) * 128 + ct * 16 + g * 4] = st;
    }
}

extern "C" void kernel_launch(void* const* d_in, const int* in_sizes, int n_in,
                              void* d_out, int out_size, void* d_ws, size_t ws_size,
                              hipStream_t stream)
{
    const float* hs = (const float*)d_in[0];
    const float* os = (const float*)d_in[1];
    const float* Wh = (const float*)d_in[4];
    const float* ah = (const float*)d_in[5];
    const float* Wo = (const float*)d_in[6];
    const float* ao = (const float*)d_in[7];
    float* out = (float*)d_out;

    u16t* h1T = (u16t*)d_ws;             // 4,194,304 u16
    u16t* x2  = h1T + 4194304;           // 4,194,304 u16
    u16t* h2T = x2 + 4194304;            // 1,048,576 u16
    u16t* WoT = h2T + 1048576;           // 65,536 u16
    float* f1a = (float*)(WoT + 65536);  // 32,768 f32
    float* f2a = f1a + 32768;
    float* f1p = f2a + 32768;            // 16,384 f32 (2 halves x 8192)
    float* f2p = f1p + 16384;            // 16,384 f32

    proj1_kernel<<<256, 512, 0, stream>>>(hs, os, Wh, Wo, ah, h1T, WoT, f1a, f2a);
    attn0_kernel<<<512, 256, 0, stream>>>(h1T, f1a, f2a, x2);
    proj2_kernel<<<256, 256, 0, stream>>>(x2, WoT, ao, h2T, f1p, f2p);
    attn1_kernel<<<256, 256, 0, stream>>>(h2T, f1p, f2p, out);
}